// Round 16
// baseline (522.861 us; speedup 1.0000x reference)
//
#include <hip/hip_runtime.h>

#define TT 200
#define XD 65
#define ROWSTR (TT * XD)  // 13000

typedef _Float16 h2 __attribute__((ext_vector_type(2)));
typedef _Float16 half8 __attribute__((ext_vector_type(8)));
typedef float f32x4 __attribute__((ext_vector_type(4)));

#define MFMA16 __builtin_amdgcn_mfma_f32_16x16x32_f16

// ---- ws dword offsets: prepacked f16 B-fragment pools + feat A-frag stream ----
#define GOFF_WXC 0
#define GOFF_WXV 8192
#define GOFF_WHC 16384
#define GOFF_WHV 24576
#define GOFF_SCC 32768
#define GOFF_SCV 34816
#define GOFF_SVV 36864
#define GOFF_SVC 38912
#define GOFF_PC0 40960
#define GOFF_PV0 43008
#define GOFF_PC1 45056
#define GOFF_PV1 46080
#define GTOT     47104
#define WS_X     47104ull  // feats: 512 b * 200 t * 128 dw (compact f16 pairs)

// ---- LDS dword offsets: Wh pools + tiles = 79,936 B -> 2 blocks/CU ----
#define L_WHC 0       // 8192 dw
#define L_WHV 8192    // 8192 dw
#define L_HC0 16384   // 512-dw tiles: [16 rows][64 f16] swizzled; only rows {0,4,8,12} used
#define L_HC1 16896
#define L_HV0 17408
#define L_HV1 17920
#define L_Y0C0 18432
#define L_Y0C1 18944
#define L_Y0V  19456
#define L_PART 19968  // 16 floats
#define L_TOT  19984  // 79,936 B

__device__ __forceinline__ unsigned pk(float lo, float hi) {
  union { h2 h; unsigned u; } c;
  c.h.x = (_Float16)lo;
  c.h.y = (_Float16)hi;
  return c.u;
}

__device__ __forceinline__ float fexp2(float x) {
#if __has_builtin(__builtin_amdgcn_exp2f)
  return __builtin_amdgcn_exp2f(x);
#else
  return __expf(x * 0.6931471805599453f);
#endif
}
__device__ __forceinline__ float frcp(float x) {
#if __has_builtin(__builtin_amdgcn_rcpf)
  return __builtin_amdgcn_rcpf(x);
#else
  return 1.0f / x;
#endif
}
__device__ __forceinline__ float sigm(float x) { return frcp(1.f + fexp2(x * -1.44269504f)); }
__device__ __forceinline__ float tanh_fast(float x) {
  return fmaf(2.f, frcp(1.f + fexp2(x * -2.88539008f)), -1.f);
}
__device__ __forceinline__ float leaky(float x) { return x > 0.0f ? x : 0.3f * x; }
__device__ __forceinline__ f32x4 sp4(float v) { f32x4 r = {v, v, v, v}; return r; }

// XOR swizzle within a [16][128B] tile
__device__ __forceinline__ int swz(int b) { return b ^ ((b >> 3) & 0x70); }

// A-frag: row = lane&15, k = kh*32 + 8*(lane>>4) + i
__device__ __forceinline__ half8 lda(const char* smc, int dwoff, int kh, int lane) {
  int byte = (lane & 15) * 128 + kh * 64 + ((lane >> 4) << 4);
  union { uint4 u; half8 h; } c;
  c.u = *(const uint4*)(smc + (dwoff << 2) + swz(byte));
  return c.h;
}
// B-frag from LDS pool
__device__ __forceinline__ half8 ldb(const unsigned* m, int n, int kh, int lane) {
  union { uint4 u; half8 h; } c;
  c.u = *(const uint4*)(m + (((n * 2 + kh) * 64 + lane) << 2));
  return c.h;
}
// B-frag from global ws pool
__device__ __forceinline__ half8 ldg8(const unsigned* ws, int off, int n, int kh, int lane) {
  union { uint4 u; half8 h; } c;
  c.u = *(const uint4*)(ws + off + (((n * 2 + kh) * 64 + lane) << 2));
  return c.h;
}

// ---- prepack: f32 weights -> f16 B-fragment pools in ws (verified) ----
extern "C" __global__ void prepack(const float* __restrict__ Wxc, const float* __restrict__ Wxv,
                                   const float* __restrict__ Whc, const float* __restrict__ Whv,
                                   const float* __restrict__ Wscc, const float* __restrict__ Wscv,
                                   const float* __restrict__ Wsvv, const float* __restrict__ Wsvc,
                                   const float* __restrict__ Wpc0, const float* __restrict__ Wpv0,
                                   const float* __restrict__ Wpc1, const float* __restrict__ Wpv1,
                                   unsigned* __restrict__ wsout) {
  int idx = blockIdx.x * 256 + threadIdx.x;
  if (idx >= GTOT) return;
  const float* W; int base, ncol;
  if      (idx < GOFF_WXV) { W = Wxc;  base = GOFF_WXC; ncol = 256; }
  else if (idx < GOFF_WHC) { W = Wxv;  base = GOFF_WXV; ncol = 256; }
  else if (idx < GOFF_WHV) { W = Whc;  base = GOFF_WHC; ncol = 256; }
  else if (idx < GOFF_SCC) { W = Whv;  base = GOFF_WHV; ncol = 256; }
  else if (idx < GOFF_SCV) { W = Wscc; base = GOFF_SCC; ncol = 64; }
  else if (idx < GOFF_SVV) { W = Wscv; base = GOFF_SCV; ncol = 64; }
  else if (idx < GOFF_SVC) { W = Wsvv; base = GOFF_SVV; ncol = 64; }
  else if (idx < GOFF_PC0) { W = Wsvc; base = GOFF_SVC; ncol = 64; }
  else if (idx < GOFF_PV0) { W = Wpc0; base = GOFF_PC0; ncol = 64; }
  else if (idx < GOFF_PC1) { W = Wpv0; base = GOFF_PV0; ncol = 64; }
  else if (idx < GOFF_PV1) { W = Wpc1; base = GOFF_PC1; ncol = 32; }
  else                     { W = Wpv1; base = GOFF_PV1; ncol = 32; }
  int local = idx - base;
  int d = local & 3, lane = (local >> 2) & 63, nk = local >> 8;
  int kh = nk & 1, n = nk >> 1;
  int k0 = kh * 32 + ((lane >> 4) << 3) + (d << 1);
  int c = n * 16 + (lane & 15);
  wsout[idx] = pk(W[k0 * ncol + c], W[(k0 + 1) * ncol + c]);
}

// ---- xpack: feats -> compact f16 pair stream [b512][t][row4][32dw] ----
extern "C" __global__ void xpack(const float* __restrict__ x, unsigned* __restrict__ wsx) {
  int t = blockIdx.x;   // 200
  int b = blockIdx.y;   // 512
  int tid = threadIdx.x;  // 128
  int row4 = tid >> 5, kdw = tid & 31;
  const float* p = x + (size_t)(b * 4 + row4) * ROWSTR + t * XD + kdw * 2;
  wsx[((size_t)b * TT + t) * 128 + tid] = pk(p[0], p[1]);
}

// One RNN step; parity constants compile-time via 2x-unrolled caller.
// Batch row br = l4 lives at C/tile row l4*4; each lane owns 1 (row, unit) cell.
// fC/fD fragments are NOT hoisted (arch-VGPR budget); loaded from L2-hot ws at use.
#define STEP(T, HCUR, HNEW, HVCUR, HVNEW, Y0W, Y0P, FC0, FC1, FN0, FN1)                       \
  {                                                                                           \
    if ((T) >= 2 && wid == 7 && lane < 4) {                                                   \
      float pc = sigm(smf[L_PART + lane] + smf[L_PART + 4 + lane] + bfc);                     \
      float pv = sigm(smf[L_PART + 8 + lane] + smf[L_PART + 12 + lane] + bfv);                \
      o2[(size_t)(r0 + lane) * TT + ((T) - 2)] = make_float2(pc, pv * pc);                    \
    }                                                                                         \
    half8 hv0 = lda(smc, HVCUR, 0, lane), hv1 = lda(smc, HVCUR, 1, lane);                     \
    if (cw) {                                                                                 \
      half8 hc0 = lda(smc, HCUR, 0, lane), hc1 = lda(smc, HCUR, 1, lane);                     \
      f32x4 a0_ = sp4(bgate[0]), a1_ = sp4(bgate[1]), a2_ = sp4(bgate[2]),                    \
            a3_ = sp4(bgate[3]);                                                              \
      __builtin_amdgcn_s_setprio(1);                                                          \
      a0_ = MFMA16(FC0, wxF[0], a0_, 0, 0, 0);                                                \
      a0_ = MFMA16(FC1, wxF[1], a0_, 0, 0, 0);                                                \
      a0_ = MFMA16(hc0, ldb(sm + L_WHC, wq, 0, lane), a0_, 0, 0, 0);                          \
      a0_ = MFMA16(hc1, ldb(sm + L_WHC, wq, 1, lane), a0_, 0, 0, 0);                          \
      a1_ = MFMA16(FC0, wxF[2], a1_, 0, 0, 0);                                                \
      a1_ = MFMA16(FC1, wxF[3], a1_, 0, 0, 0);                                                \
      a1_ = MFMA16(hc0, ldb(sm + L_WHC, wq + 4, 0, lane), a1_, 0, 0, 0);                      \
      a1_ = MFMA16(hc1, ldb(sm + L_WHC, wq + 4, 1, lane), a1_, 0, 0, 0);                      \
      a2_ = MFMA16(FC0, wxF[4], a2_, 0, 0, 0);                                                \
      a2_ = MFMA16(FC1, wxF[5], a2_, 0, 0, 0);                                                \
      a2_ = MFMA16(hc0, ldb(sm + L_WHC, wq + 8, 0, lane), a2_, 0, 0, 0);                      \
      a2_ = MFMA16(hc1, ldb(sm + L_WHC, wq + 8, 1, lane), a2_, 0, 0, 0);                      \
      a3_ = MFMA16(FC0, wxF[6], a3_, 0, 0, 0);                                                \
      a3_ = MFMA16(FC1, wxF[7], a3_, 0, 0, 0);                                                \
      a3_ = MFMA16(hc0, ldb(sm + L_WHC, wq + 12, 0, lane), a3_, 0, 0, 0);                     \
      a3_ = MFMA16(hc1, ldb(sm + L_WHC, wq + 12, 1, lane), a3_, 0, 0, 0);                     \
      f32x4 pscc = sp4(0.f), pscv = sp4(0.f);                                                 \
      pscc = MFMA16(hc0, fA0, pscc, 0, 0, 0);                                                 \
      pscc = MFMA16(hc1, fA1, pscc, 0, 0, 0);                                                 \
      pscv = MFMA16(hv0, fB0, pscv, 0, 0, 0);                                                 \
      pscv = MFMA16(hv1, fB1, pscv, 0, 0, 0);                                                 \
      __builtin_amdgcn_s_setprio(0);                                                          \
      {                                                                                       \
        bool gp = gprev >= 0.5f;                                                              \
        float f = sigm(a0_[0]), ii = sigm(a1_[0]), o = sigm(a2_[0]);                          \
        float gc = tanh_fast(a3_[0]);                                                         \
        float sh = tanh_fast(gp ? pscv[0] : pscc[0]);                                         \
        float s = sh + ii * gc + (gp ? 0.f : f * st);                                         \
        st = s;                                                                               \
        float hcn = o * tanh_fast(s);                                                         \
        *(_Float16*)(smc + ((HNEW) << 2) + swz(l4 * 512 + col2)) = (_Float16)hcn;             \
      }                                                                                       \
    } else {                                                                                  \
      f32x4 a0_ = sp4(bgate[0]), a1_ = sp4(bgate[1]), a2_ = sp4(bgate[2]),                    \
            a3_ = sp4(bgate[3]);                                                              \
      __builtin_amdgcn_s_setprio(1);                                                          \
      a0_ = MFMA16(FC0, wxF[0], a0_, 0, 0, 0);                                                \
      a0_ = MFMA16(FC1, wxF[1], a0_, 0, 0, 0);                                                \
      a0_ = MFMA16(hv0, ldb(sm + L_WHV, wq, 0, lane), a0_, 0, 0, 0);                          \
      a0_ = MFMA16(hv1, ldb(sm + L_WHV, wq, 1, lane), a0_, 0, 0, 0);                          \
      a1_ = MFMA16(FC0, wxF[2], a1_, 0, 0, 0);                                                \
      a1_ = MFMA16(FC1, wxF[3], a1_, 0, 0, 0);                                                \
      a1_ = MFMA16(hv0, ldb(sm + L_WHV, wq + 4, 0, lane), a1_, 0, 0, 0);                      \
      a1_ = MFMA16(hv1, ldb(sm + L_WHV, wq + 4, 1, lane), a1_, 0, 0, 0);                      \
      a2_ = MFMA16(FC0, wxF[4], a2_, 0, 0, 0);                                                \
      a2_ = MFMA16(FC1, wxF[5], a2_, 0, 0, 0);                                                \
      a2_ = MFMA16(hv0, ldb(sm + L_WHV, wq + 8, 0, lane), a2_, 0, 0, 0);                      \
      a2_ = MFMA16(hv1, ldb(sm + L_WHV, wq + 8, 1, lane), a2_, 0, 0, 0);                      \
      a3_ = MFMA16(FC0, wxF[6], a3_, 0, 0, 0);                                                \
      a3_ = MFMA16(FC1, wxF[7], a3_, 0, 0, 0);                                                \
      a3_ = MFMA16(hv0, ldb(sm + L_WHV, wq + 12, 0, lane), a3_, 0, 0, 0);                     \
      a3_ = MFMA16(hv1, ldb(sm + L_WHV, wq + 12, 1, lane), a3_, 0, 0, 0);                     \
      f32x4 psvv = sp4(0.f);                                                                  \
      psvv = MFMA16(hv0, fA0, psvv, 0, 0, 0);                                                 \
      psvv = MFMA16(hv1, fA1, psvv, 0, 0, 0);                                                 \
      __builtin_amdgcn_s_setprio(0);                                                          \
      if ((T) >= 1) {                                                                         \
        f32x4 apv = sp4(b0u);                                                                 \
        apv = MFMA16(hv0, ldg8(ws, GOFF_PV0, wq, 0, lane), apv, 0, 0, 0);                     \
        apv = MFMA16(hv1, ldg8(ws, GOFF_PV0, wq, 1, lane), apv, 0, 0, 0);                     \
        *(_Float16*)(smc + (L_Y0V << 2) + swz(l4 * 512 + col2)) = (_Float16)leaky(apv[0]);    \
      }                                                                                       \
      fvv = sigm(a0_[0]);                                                                     \
      ivv = sigm(a1_[0]);                                                                     \
      ovv = sigm(a2_[0]);                                                                     \
      gvv = tanh_fast(a3_[0]);                                                                \
      psv = psvv[0];                                                                          \
    }                                                                                         \
    {                                                                                         \
      const int tn_ = ((T) + 1 < TT) ? (T) + 1 : (TT - 1);                                    \
      union { uint4 u; half8 h; } u0_, u1_;                                                   \
      u0_.u = xfr[tn_ * 32];                                                                  \
      u1_.u = xfr[tn_ * 32 + 4];                                                              \
      FN0 = u0_.h;                                                                            \
      FN1 = u1_.h;                                                                            \
      gnext = xck[tn_ * XD];                                                                  \
    }                                                                                         \
    __syncthreads(); /* B1 */                                                                 \
    half8 hn0 = lda(smc, HNEW, 0, lane), hn1 = lda(smc, HNEW, 1, lane);                       \
    if (!cw) {                                                                                \
      f32x4 psvc = sp4(0.f);                                                                  \
      psvc = MFMA16(hn0, fB0, psvc, 0, 0, 0);                                                 \
      psvc = MFMA16(hn1, fB1, psvc, 0, 0, 0);                                                 \
      {                                                                                       \
        bool g = gcur >= 0.5f;                                                                \
        float sh = tanh_fast(g ? psv + psvc[0] : psv);                                        \
        float s = sh + (g ? fvv * st + ivv * gvv : st);                                       \
        st = s;                                                                               \
        float hvn = g ? ovv * tanh_fast(s) : hvold;                                           \
        hvold = hvn;                                                                          \
        *(_Float16*)(smc + ((HVNEW) << 2) + swz(l4 * 512 + col2)) = (_Float16)hvn;            \
      }                                                                                       \
    } else {                                                                                  \
      f32x4 ap = sp4(b0u);                                                                    \
      ap = MFMA16(hn0, ldg8(ws, GOFF_PC0, wq, 0, lane), ap, 0, 0, 0);                         \
      ap = MFMA16(hn1, ldg8(ws, GOFF_PC0, wq, 1, lane), ap, 0, 0, 0);                         \
      *(_Float16*)(smc + ((Y0W) << 2) + swz(l4 * 512 + col2)) = (_Float16)leaky(ap[0]);       \
      if ((T) >= 1) {                                                                         \
        const int asrc = (wid < 2) ? (Y0P) : L_Y0V;                                           \
        const int hoff_ = (wid < 2) ? GOFF_PC1 : GOFF_PV1;                                    \
        f32x4 ah = sp4(b1h);                                                                  \
        ah = MFMA16(lda(smc, asrc, 0, lane), ldg8(ws, hoff_, wid & 1, 0, lane), ah, 0, 0, 0); \
        ah = MFMA16(lda(smc, asrc, 1, lane), ldg8(ws, hoff_, wid & 1, 1, lane), ah, 0, 0, 0); \
        {                                                                                     \
          float tq = leaky(ah[0]) * wfh;                                                      \
          tq += __shfl_xor(tq, 1, 64);                                                        \
          tq += __shfl_xor(tq, 2, 64);                                                        \
          tq += __shfl_xor(tq, 4, 64);                                                        \
          tq += __shfl_xor(tq, 8, 64);                                                        \
          if (l15 == 0)                                                                       \
            smf[L_PART + ((wid < 2) ? 0 : 8) + (wid & 1) * 4 + l4] = tq;                      \
        }                                                                                     \
      }                                                                                       \
    }                                                                                         \
    gprev = gcur;                                                                             \
    gcur = gnext;                                                                             \
    __syncthreads(); /* B2 */                                                                 \
  }

// ---- fused RNN: 4 rows/block, 512 blocks, 8 waves; Wh in LDS; fC/fD streamed ----
// Target: arch VGPR <= 80 so arch + AGPR-accum quantum <= 128 -> 2 blocks/CU.
extern "C" __global__ void __launch_bounds__(512, 1)
rnn_mfma(const float* __restrict__ x,
         const float* __restrict__ bxc, const float* __restrict__ bxv,
         const float* __restrict__ bpc0, const float* __restrict__ bpc1,
         const float* __restrict__ Wfcc, const float* __restrict__ bfcc,
         const float* __restrict__ bpv0, const float* __restrict__ bpv1,
         const float* __restrict__ Wfcv, const float* __restrict__ bfcv,
         const unsigned* __restrict__ ws, float* __restrict__ out) {
  extern __shared__ unsigned sm[];
  char* smc = (char*)sm;
  float* smf = (float*)sm;
  const int tid = threadIdx.x;
  const int lane = tid & 63, wid = tid >> 6;
  const int l15 = lane & 15, l4 = lane >> 4;
  const int wq = wid & 3;
  const bool cw = wid < 4;
  const int r0 = blockIdx.x * 4;

  // Whc|Whv pools -> LDS (ws dwords [16384, 32768))
  for (int i = tid; i < 4096; i += 512) ((uint4*)sm)[i] = ((const uint4*)ws)[4096 + i];
  // zero tiles/part
  for (int i = 16384 + tid; i < L_TOT; i += 512) sm[i] = 0;

  // per-wave constants
  float bgate[4];
#pragma unroll
  for (int m = 0; m < 4; ++m) bgate[m] = (cw ? bxc : bxv)[(wq + 4 * m) * 16 + l15];
  const float b0u = (cw ? bpc0 : bpv0)[16 * wq + l15];
  const float b1h = (wid < 2 ? bpc1 : bpv1)[16 * (wid & 1) + l15];
  const float wfh = (wid < 2 ? Wfcc : Wfcv)[16 * (wid & 1) + l15];
  const float bfc = bfcc[0], bfv = bfcv[0];

  // hoisted B-fragments: Wx (critical path) + recurrence-critical fA/fB only
  half8 wxF[8];
#pragma unroll
  for (int m = 0; m < 4; ++m) {
    wxF[2 * m] = ldg8(ws, cw ? GOFF_WXC : GOFF_WXV, wq + 4 * m, 0, lane);
    wxF[2 * m + 1] = ldg8(ws, cw ? GOFF_WXC : GOFF_WXV, wq + 4 * m, 1, lane);
  }
  half8 fA0, fA1, fB0, fB1;
  if (cw) {
    fA0 = ldg8(ws, GOFF_SCC, wq, 0, lane); fA1 = ldg8(ws, GOFF_SCC, wq, 1, lane);
    fB0 = ldg8(ws, GOFF_SCV, wq, 0, lane); fB1 = ldg8(ws, GOFF_SCV, wq, 1, lane);
  } else {
    fA0 = ldg8(ws, GOFF_SVV, wq, 0, lane); fA1 = ldg8(ws, GOFF_SVV, wq, 1, lane);
    fB0 = ldg8(ws, GOFF_SVC, wq, 0, lane); fB1 = ldg8(ws, GOFF_SVC, wq, 1, lane);
  }

  // feat A-frag stream: tile row l15 -> batch row l15>>2 (4-way dup for rows %4 != 0)
  const uint4* xfr = (const uint4*)(ws + WS_X) + (size_t)blockIdx.x * (TT * 32) +
                     (l15 >> 2) * 8 + l4;
  half8 fx0, fx1, fy0, fy1;
  {
    union { uint4 u; half8 h; } u0_, u1_;
    u0_.u = xfr[0];
    u1_.u = xfr[4];
    fx0 = u0_.h;
    fx1 = u1_.h;
  }

  // clicks in registers: lane handles batch row l4
  const float* xck = x + (size_t)(r0 + l4) * ROWSTR + 64;
  float gprev = 0.f;  // click(t-1); g(-1)=0
  float gcur = xck[0], gnext;

  float st = 0.f;     // s_c (c-waves) / s_v (v-waves)
  float hvold = 0.f;  // h_v reg (v-waves)
  float fvv, ivv, ovv, gvv, psv;
  const int col2 = (16 * wq + l15) * 2;
  float2* o2 = (float2*)out;

  __syncthreads();

  for (int t = 0; t < TT; t += 2) {
    STEP(t,     L_HC0, L_HC1, L_HV0, L_HV1, L_Y0C0, L_Y0C1, fx0, fx1, fy0, fy1)
    STEP(t + 1, L_HC1, L_HC0, L_HV1, L_HV0, L_Y0C1, L_Y0C0, fy0, fy1, fx0, fx1)
  }

  // ---- epilogue: out(198), out(199) ----
  if (wid == 7 && lane < 4) {
    float pc = sigm(smf[L_PART + lane] + smf[L_PART + 4 + lane] + bfc);
    float pv = sigm(smf[L_PART + 8 + lane] + smf[L_PART + 12 + lane] + bfv);
    o2[(size_t)(r0 + lane) * TT + (TT - 2)] = make_float2(pc, pv * pc);
  }
  if (!cw) {  // pv0(199): h_v(199) in L_HV0 (t=199 odd -> HVNEW = L_HV0)
    f32x4 apv = sp4(b0u);
    apv = MFMA16(lda(smc, L_HV0, 0, lane), ldg8(ws, GOFF_PV0, wq, 0, lane), apv, 0, 0, 0);
    apv = MFMA16(lda(smc, L_HV0, 1, lane), ldg8(ws, GOFF_PV0, wq, 1, lane), apv, 0, 0, 0);
    *(_Float16*)(smc + (L_Y0V << 2) + swz(l4 * 512 + col2)) = (_Float16)leaky(apv[0]);
  }
  __syncthreads();
  if (cw) {  // heads(199): y0c(199) in L_Y0C1
    const int asrc = (wid < 2) ? L_Y0C1 : L_Y0V;
    const int hoff_ = (wid < 2) ? GOFF_PC1 : GOFF_PV1;
    f32x4 ah = sp4(b1h);
    ah = MFMA16(lda(smc, asrc, 0, lane), ldg8(ws, hoff_, wid & 1, 0, lane), ah, 0, 0, 0);
    ah = MFMA16(lda(smc, asrc, 1, lane), ldg8(ws, hoff_, wid & 1, 1, lane), ah, 0, 0, 0);
    float tq = leaky(ah[0]) * wfh;
    tq += __shfl_xor(tq, 1, 64);
    tq += __shfl_xor(tq, 2, 64);
    tq += __shfl_xor(tq, 4, 64);
    tq += __shfl_xor(tq, 8, 64);
    if (l15 == 0)
      smf[L_PART + ((wid < 2) ? 0 : 8) + (wid & 1) * 4 + l4] = tq;
  }
  __syncthreads();
  if (wid == 0 && lane < 4) {
    float pc = sigm(smf[L_PART + lane] + smf[L_PART + 4 + lane] + bfc);
    float pv = sigm(smf[L_PART + 8 + lane] + smf[L_PART + 12 + lane] + bfv);
    o2[(size_t)(r0 + lane) * TT + (TT - 1)] = make_float2(pc, pv * pc);
  }
}

extern "C" void kernel_launch(void* const* d_in, const int* in_sizes, int n_in,
                              void* d_out, int out_size, void* d_ws, size_t ws_size,
                              hipStream_t stream) {
  const float* x    = (const float*)d_in[0];
  const float* Wxc  = (const float*)d_in[1];
  const float* bxc  = (const float*)d_in[2];
  const float* Whc  = (const float*)d_in[3];
  const float* Wxv  = (const float*)d_in[4];
  const float* bxv  = (const float*)d_in[5];
  const float* Whv  = (const float*)d_in[6];
  const float* Wscc = (const float*)d_in[7];
  const float* Wscv = (const float*)d_in[8];
  const float* Wsvv = (const float*)d_in[9];
  const float* Wsvc = (const float*)d_in[10];
  const float* Wpc0 = (const float*)d_in[11];
  const float* bpc0 = (const float*)d_in[12];
  const float* Wpc1 = (const float*)d_in[13];
  const float* bpc1 = (const float*)d_in[14];
  const float* Wfcc = (const float*)d_in[15];
  const float* bfcc = (const float*)d_in[16];
  const float* Wpv0 = (const float*)d_in[17];
  const float* bpv0 = (const float*)d_in[18];
  const float* Wpv1 = (const float*)d_in[19];
  const float* bpv1 = (const float*)d_in[20];
  const float* Wfcv = (const float*)d_in[21];
  const float* bfcv = (const float*)d_in[22];
  float* out = (float*)d_out;
  unsigned* wsbuf = (unsigned*)d_ws;

  prepack<<<184, 256, 0, stream>>>(Wxc, Wxv, Whc, Whv, Wscc, Wscv, Wsvv, Wsvc,
                                   Wpc0, Wpv0, Wpc1, Wpv1, wsbuf);
  xpack<<<dim3(TT, 512), 128, 0, stream>>>(x, wsbuf + WS_X);

  (void)hipFuncSetAttribute(reinterpret_cast<const void*>(rnn_mfma),
                            hipFuncAttributeMaxDynamicSharedMemorySize, L_TOT * 4);
  rnn_mfma<<<512, 512, L_TOT * 4, stream>>>(
      x, bxc, bxv, bpc0, bpc1, Wfcc, bfcc, bpv0, bpv1, Wfcv, bfcv, wsbuf, out);
}

// Round 17
// 261.546 us; speedup vs baseline: 1.9991x; 1.9991x over previous
//
#include <hip/hip_runtime.h>

#define TT 200
#define XD 65
#define ROWSTR (TT * XD)  // 13000

typedef _Float16 h2 __attribute__((ext_vector_type(2)));
typedef _Float16 half8 __attribute__((ext_vector_type(8)));
typedef float f32x4 __attribute__((ext_vector_type(4)));

#define MFMA16 __builtin_amdgcn_mfma_f32_16x16x32_f16

// ---- ws dword offsets: prepacked f16 B-fragment pools + feat A-frag stream ----
#define GOFF_WXC 0
#define GOFF_WXV 8192
#define GOFF_WHC 16384
#define GOFF_WHV 24576
#define GOFF_SCC 32768
#define GOFF_SCV 34816
#define GOFF_SVV 36864
#define GOFF_SVC 38912
#define GOFF_PC0 40960
#define GOFF_PV0 43008
#define GOFF_PC1 45056
#define GOFF_PV1 46080
#define GTOT     47104
#define WS_X     47104ull  // feats: 256 b * 200 t * 256 dw (compact f16 pairs)

// ---- LDS dword offsets (tiles only) ----
#define L_HC0 0      // 512-dw tiles: [16 rows][64 f16] swizzled; rows {2,3,6,7,...} stay 0
#define L_HC1 512
#define L_HV0 1024
#define L_HV1 1536
#define L_Y0C0 2048
#define L_Y0C1 2560
#define L_Y0V  3072
#define L_PART 3584  // 32 floats
#define L_TOT  3616  // 14,464 B

__device__ __forceinline__ unsigned pk(float lo, float hi) {
  union { h2 h; unsigned u; } c;
  c.h.x = (_Float16)lo;
  c.h.y = (_Float16)hi;
  return c.u;
}

__device__ __forceinline__ float fexp2(float x) {
#if __has_builtin(__builtin_amdgcn_exp2f)
  return __builtin_amdgcn_exp2f(x);
#else
  return __expf(x * 0.6931471805599453f);
#endif
}
__device__ __forceinline__ float frcp(float x) {
#if __has_builtin(__builtin_amdgcn_rcpf)
  return __builtin_amdgcn_rcpf(x);
#else
  return 1.0f / x;
#endif
}
__device__ __forceinline__ float sigm(float x) { return frcp(1.f + fexp2(x * -1.44269504f)); }
__device__ __forceinline__ float tanh_fast(float x) {
  return fmaf(2.f, frcp(1.f + fexp2(x * -2.88539008f)), -1.f);
}
__device__ __forceinline__ float leaky(float x) { return x > 0.0f ? x : 0.3f * x; }
__device__ __forceinline__ f32x4 sp4(float v) { f32x4 r = {v, v, v, v}; return r; }

// XOR swizzle within a [16][128B] tile
__device__ __forceinline__ int swz(int b) { return b ^ ((b >> 3) & 0x70); }

// A-frag: row = lane&15, k = kh*32 + 8*(lane>>4) + i
__device__ __forceinline__ half8 lda(const char* smc, int dwoff, int kh, int lane) {
  int byte = (lane & 15) * 128 + kh * 64 + ((lane >> 4) << 4);
  union { uint4 u; half8 h; } c;
  c.u = *(const uint4*)(smc + (dwoff << 2) + swz(byte));
  return c.h;
}
// B-frag from global ws pool
__device__ __forceinline__ half8 ldg8(const unsigned* ws, int off, int n, int kh, int lane) {
  union { uint4 u; half8 h; } c;
  c.u = *(const uint4*)(ws + off + (((n * 2 + kh) * 64 + lane) << 2));
  return c.h;
}

// ---- prepack: f32 weights -> f16 B-fragment pools in ws (verified) ----
extern "C" __global__ void prepack(const float* __restrict__ Wxc, const float* __restrict__ Wxv,
                                   const float* __restrict__ Whc, const float* __restrict__ Whv,
                                   const float* __restrict__ Wscc, const float* __restrict__ Wscv,
                                   const float* __restrict__ Wsvv, const float* __restrict__ Wsvc,
                                   const float* __restrict__ Wpc0, const float* __restrict__ Wpv0,
                                   const float* __restrict__ Wpc1, const float* __restrict__ Wpv1,
                                   unsigned* __restrict__ wsout) {
  int idx = blockIdx.x * 256 + threadIdx.x;
  if (idx >= GTOT) return;
  const float* W; int base, ncol;
  if      (idx < GOFF_WXV) { W = Wxc;  base = GOFF_WXC; ncol = 256; }
  else if (idx < GOFF_WHC) { W = Wxv;  base = GOFF_WXV; ncol = 256; }
  else if (idx < GOFF_WHV) { W = Whc;  base = GOFF_WHC; ncol = 256; }
  else if (idx < GOFF_SCC) { W = Whv;  base = GOFF_WHV; ncol = 256; }
  else if (idx < GOFF_SCV) { W = Wscc; base = GOFF_SCC; ncol = 64; }
  else if (idx < GOFF_SVV) { W = Wscv; base = GOFF_SCV; ncol = 64; }
  else if (idx < GOFF_SVC) { W = Wsvv; base = GOFF_SVV; ncol = 64; }
  else if (idx < GOFF_PC0) { W = Wsvc; base = GOFF_SVC; ncol = 64; }
  else if (idx < GOFF_PV0) { W = Wpc0; base = GOFF_PC0; ncol = 64; }
  else if (idx < GOFF_PC1) { W = Wpv0; base = GOFF_PV0; ncol = 64; }
  else if (idx < GOFF_PV1) { W = Wpc1; base = GOFF_PC1; ncol = 32; }
  else                     { W = Wpv1; base = GOFF_PV1; ncol = 32; }
  int local = idx - base;
  int d = local & 3, lane = (local >> 2) & 63, nk = local >> 8;
  int kh = nk & 1, n = nk >> 1;
  int k0 = kh * 32 + ((lane >> 4) << 3) + (d << 1);
  int c = n * 16 + (lane & 15);
  wsout[idx] = pk(W[k0 * ncol + c], W[(k0 + 1) * ncol + c]);
}

// ---- xpack: feats -> compact f16 pair stream [b][t][row8][32dw] ----
extern "C" __global__ void xpack(const float* __restrict__ x, unsigned* __restrict__ wsx) {
  int t = blockIdx.x;   // 200
  int b = blockIdx.y;   // 256
  int tid = threadIdx.x;  // 256
  int row8 = tid >> 5, kdw = tid & 31;
  const float* p = x + (size_t)(b * 8 + row8) * ROWSTR + t * XD + kdw * 2;
  wsx[((size_t)b * TT + t) * 256 + tid] = pk(p[0], p[1]);
}

// One RNN step; parity constants compile-time via 2x-unrolled caller.
// Batch row br = l4*2+q (q in {0,1}) lives at C/tile row l4*4+q.
#define STEP(T, HCUR, HNEW, HVCUR, HVNEW, Y0W, Y0P, FC0, FC1, FN0, FN1)                       \
  {                                                                                           \
    if ((T) >= 2 && wid == 7 && lane < 8) {                                                   \
      float pc = sigm(smf[L_PART + lane] + smf[L_PART + 8 + lane] + bfc);                     \
      float pv = sigm(smf[L_PART + 16 + lane] + smf[L_PART + 24 + lane] + bfv);               \
      o2[(size_t)(r0 + lane) * TT + ((T) - 2)] = make_float2(pc, pv * pc);                    \
    }                                                                                         \
    half8 hv0 = lda(smc, HVCUR, 0, lane), hv1 = lda(smc, HVCUR, 1, lane);                     \
    if (cw) {                                                                                 \
      half8 hc0 = lda(smc, HCUR, 0, lane), hc1 = lda(smc, HCUR, 1, lane);                     \
      f32x4 a0_ = sp4(bgate[0]), a1_ = sp4(bgate[1]), a2_ = sp4(bgate[2]),                    \
            a3_ = sp4(bgate[3]);                                                              \
      __builtin_amdgcn_s_setprio(1);                                                          \
      a0_ = MFMA16(FC0, wxF[0], a0_, 0, 0, 0);                                                \
      a0_ = MFMA16(FC1, wxF[1], a0_, 0, 0, 0);                                                \
      a0_ = MFMA16(hc0, whF[0], a0_, 0, 0, 0);                                                \
      a0_ = MFMA16(hc1, whF[1], a0_, 0, 0, 0);                                                \
      a1_ = MFMA16(FC0, wxF[2], a1_, 0, 0, 0);                                                \
      a1_ = MFMA16(FC1, wxF[3], a1_, 0, 0, 0);                                                \
      a1_ = MFMA16(hc0, whF[2], a1_, 0, 0, 0);                                                \
      a1_ = MFMA16(hc1, whF[3], a1_, 0, 0, 0);                                                \
      a2_ = MFMA16(FC0, wxF[4], a2_, 0, 0, 0);                                                \
      a2_ = MFMA16(FC1, wxF[5], a2_, 0, 0, 0);                                                \
      a2_ = MFMA16(hc0, whF[4], a2_, 0, 0, 0);                                                \
      a2_ = MFMA16(hc1, whF[5], a2_, 0, 0, 0);                                                \
      a3_ = MFMA16(FC0, wxF[6], a3_, 0, 0, 0);                                                \
      a3_ = MFMA16(FC1, wxF[7], a3_, 0, 0, 0);                                                \
      a3_ = MFMA16(hc0, whF[6], a3_, 0, 0, 0);                                                \
      a3_ = MFMA16(hc1, whF[7], a3_, 0, 0, 0);                                                \
      f32x4 pscc = sp4(0.f), pscv = sp4(0.f);                                                 \
      pscc = MFMA16(hc0, fA0, pscc, 0, 0, 0);                                                 \
      pscc = MFMA16(hc1, fA1, pscc, 0, 0, 0);                                                 \
      pscv = MFMA16(hv0, fB0, pscv, 0, 0, 0);                                                 \
      pscv = MFMA16(hv1, fB1, pscv, 0, 0, 0);                                                 \
      __builtin_amdgcn_s_setprio(0);                                                          \
      _Pragma("unroll") for (int q = 0; q < 2; ++q) {                                         \
        bool gp = gprev[q] >= 0.5f;                                                           \
        float f = sigm(a0_[q]), ii = sigm(a1_[q]), o = sigm(a2_[q]);                          \
        float gc = tanh_fast(a3_[q]);                                                         \
        float sh = tanh_fast(gp ? pscv[q] : pscc[q]);                                         \
        float s = sh + ii * gc + (gp ? 0.f : f * st[q]);                                      \
        st[q] = s;                                                                            \
        float hcn = o * tanh_fast(s);                                                         \
        *(_Float16*)(smc + ((HNEW) << 2) + swz((l4 * 4 + q) * 128 + col2)) = (_Float16)hcn;   \
      }                                                                                       \
    } else {                                                                                  \
      f32x4 a0_ = sp4(bgate[0]), a1_ = sp4(bgate[1]), a2_ = sp4(bgate[2]),                    \
            a3_ = sp4(bgate[3]);                                                              \
      __builtin_amdgcn_s_setprio(1);                                                          \
      a0_ = MFMA16(FC0, wxF[0], a0_, 0, 0, 0);                                                \
      a0_ = MFMA16(FC1, wxF[1], a0_, 0, 0, 0);                                                \
      a0_ = MFMA16(hv0, whF[0], a0_, 0, 0, 0);                                                \
      a0_ = MFMA16(hv1, whF[1], a0_, 0, 0, 0);                                                \
      a1_ = MFMA16(FC0, wxF[2], a1_, 0, 0, 0);                                                \
      a1_ = MFMA16(FC1, wxF[3], a1_, 0, 0, 0);                                                \
      a1_ = MFMA16(hv0, whF[2], a1_, 0, 0, 0);                                                \
      a1_ = MFMA16(hv1, whF[3], a1_, 0, 0, 0);                                                \
      a2_ = MFMA16(FC0, wxF[4], a2_, 0, 0, 0);                                                \
      a2_ = MFMA16(FC1, wxF[5], a2_, 0, 0, 0);                                                \
      a2_ = MFMA16(hv0, whF[4], a2_, 0, 0, 0);                                                \
      a2_ = MFMA16(hv1, whF[5], a2_, 0, 0, 0);                                                \
      a3_ = MFMA16(FC0, wxF[6], a3_, 0, 0, 0);                                                \
      a3_ = MFMA16(FC1, wxF[7], a3_, 0, 0, 0);                                                \
      a3_ = MFMA16(hv0, whF[6], a3_, 0, 0, 0);                                                \
      a3_ = MFMA16(hv1, whF[7], a3_, 0, 0, 0);                                                \
      f32x4 psvv = sp4(0.f);                                                                  \
      psvv = MFMA16(hv0, fA0, psvv, 0, 0, 0);                                                 \
      psvv = MFMA16(hv1, fA1, psvv, 0, 0, 0);                                                 \
      __builtin_amdgcn_s_setprio(0);                                                          \
      if ((T) >= 1) {                                                                         \
        f32x4 apv = sp4(b0u);                                                                 \
        apv = MFMA16(hv0, fC0, apv, 0, 0, 0);                                                 \
        apv = MFMA16(hv1, fC1, apv, 0, 0, 0);                                                 \
        _Pragma("unroll") for (int q = 0; q < 2; ++q)                                         \
            *(_Float16*)(smc + (L_Y0V << 2) + swz((l4 * 4 + q) * 128 + col2)) =               \
                (_Float16)leaky(apv[q]);                                                      \
      }                                                                                       \
      _Pragma("unroll") for (int q = 0; q < 2; ++q) {                                         \
        fvv[q] = sigm(a0_[q]);                                                                \
        ivv[q] = sigm(a1_[q]);                                                                \
        ovv[q] = sigm(a2_[q]);                                                                \
        gvv[q] = tanh_fast(a3_[q]);                                                           \
        psv[q] = psvv[q];                                                                     \
      }                                                                                       \
    }                                                                                         \
    {                                                                                         \
      const int tn_ = ((T) + 1 < TT) ? (T) + 1 : (TT - 1);                                    \
      union { uint4 u; half8 h; } u0_, u1_;                                                   \
      u0_.u = xfr[tn_ * 64];                                                                  \
      u1_.u = xfr[tn_ * 64 + 4];                                                              \
      FN0 = u0_.h;                                                                            \
      FN1 = u1_.h;                                                                            \
      gnext[0] = xck[tn_ * XD];                                                               \
      gnext[1] = xck[ROWSTR + tn_ * XD];                                                      \
    }                                                                                         \
    __syncthreads(); /* B1 */                                                                 \
    half8 hn0 = lda(smc, HNEW, 0, lane), hn1 = lda(smc, HNEW, 1, lane);                       \
    if (!cw) {                                                                                \
      f32x4 psvc = sp4(0.f);                                                                  \
      psvc = MFMA16(hn0, fB0, psvc, 0, 0, 0);                                                 \
      psvc = MFMA16(hn1, fB1, psvc, 0, 0, 0);                                                 \
      _Pragma("unroll") for (int q = 0; q < 2; ++q) {                                         \
        bool g = gcur[q] >= 0.5f;                                                             \
        float sh = tanh_fast(g ? psv[q] + psvc[q] : psv[q]);                                  \
        float s = sh + (g ? fvv[q] * st[q] + ivv[q] * gvv[q] : st[q]);                        \
        st[q] = s;                                                                            \
        float hvn = g ? ovv[q] * tanh_fast(s) : hvold[q];                                     \
        hvold[q] = hvn;                                                                       \
        *(_Float16*)(smc + ((HVNEW) << 2) + swz((l4 * 4 + q) * 128 + col2)) = (_Float16)hvn;  \
      }                                                                                       \
    } else {                                                                                  \
      f32x4 ap = sp4(b0u);                                                                    \
      ap = MFMA16(hn0, fC0, ap, 0, 0, 0);                                                     \
      ap = MFMA16(hn1, fC1, ap, 0, 0, 0);                                                     \
      _Pragma("unroll") for (int q = 0; q < 2; ++q)                                           \
          *(_Float16*)(smc + ((Y0W) << 2) + swz((l4 * 4 + q) * 128 + col2)) =                 \
              (_Float16)leaky(ap[q]);                                                         \
      if ((T) >= 1) {                                                                         \
        const int asrc = (wid < 2) ? (Y0P) : L_Y0V;                                           \
        f32x4 ah = sp4(b1h);                                                                  \
        ah = MFMA16(lda(smc, asrc, 0, lane), fD0, ah, 0, 0, 0);                               \
        ah = MFMA16(lda(smc, asrc, 1, lane), fD1, ah, 0, 0, 0);                               \
        _Pragma("unroll") for (int q = 0; q < 2; ++q) {                                       \
          float tq = leaky(ah[q]) * wfh;                                                      \
          tq += __shfl_xor(tq, 1, 64);                                                        \
          tq += __shfl_xor(tq, 2, 64);                                                        \
          tq += __shfl_xor(tq, 4, 64);                                                        \
          tq += __shfl_xor(tq, 8, 64);                                                        \
          if (l15 == 0)                                                                       \
            smf[L_PART + ((wid < 2) ? 0 : 16) + (wid & 1) * 8 + (l4 * 2 + q)] = tq;           \
        }                                                                                     \
      }                                                                                       \
    }                                                                                         \
    _Pragma("unroll") for (int q = 0; q < 2; ++q) {                                           \
      gprev[q] = gcur[q];                                                                     \
      gcur[q] = gnext[q];                                                                     \
    }                                                                                         \
    __syncthreads(); /* B2 */                                                                 \
  }

// ---- fused RNN: 8 rows/block, 256 blocks, 8 waves, rows at C-slots q<2 ----
extern "C" __global__ void __launch_bounds__(512, 1)
rnn_mfma(const float* __restrict__ x,
         const float* __restrict__ bxc, const float* __restrict__ bxv,
         const float* __restrict__ bpc0, const float* __restrict__ bpc1,
         const float* __restrict__ Wfcc, const float* __restrict__ bfcc,
         const float* __restrict__ bpv0, const float* __restrict__ bpv1,
         const float* __restrict__ Wfcv, const float* __restrict__ bfcv,
         const unsigned* __restrict__ ws, float* __restrict__ out) {
  extern __shared__ unsigned sm[];
  char* smc = (char*)sm;
  float* smf = (float*)sm;
  const int tid = threadIdx.x;
  const int lane = tid & 63, wid = tid >> 6;
  const int l15 = lane & 15, l4 = lane >> 4;
  const int wq = wid & 3;
  const bool cw = wid < 4;
  const int r0 = blockIdx.x * 8;

  // zero all LDS (tiles/part)
  for (int i = tid; i < L_TOT; i += 512) sm[i] = 0;

  // per-wave constants
  float bgate[4];
#pragma unroll
  for (int m = 0; m < 4; ++m) bgate[m] = (cw ? bxc : bxv)[(wq + 4 * m) * 16 + l15];
  const float b0u = (cw ? bpc0 : bpv0)[16 * wq + l15];
  const float b1h = (wid < 2 ? bpc1 : bpv1)[16 * (wid & 1) + l15];
  const float wfh = (wid < 2 ? Wfcc : Wfcv)[16 * (wid & 1) + l15];
  const float bfc = bfcc[0], bfv = bfcv[0];

  // hoisted B-fragments: gate weights fully in registers
  half8 wxF[8], whF[8];
#pragma unroll
  for (int m = 0; m < 4; ++m) {
    wxF[2 * m] = ldg8(ws, cw ? GOFF_WXC : GOFF_WXV, wq + 4 * m, 0, lane);
    wxF[2 * m + 1] = ldg8(ws, cw ? GOFF_WXC : GOFF_WXV, wq + 4 * m, 1, lane);
    whF[2 * m] = ldg8(ws, cw ? GOFF_WHC : GOFF_WHV, wq + 4 * m, 0, lane);
    whF[2 * m + 1] = ldg8(ws, cw ? GOFF_WHC : GOFF_WHV, wq + 4 * m, 1, lane);
  }
  half8 fA0, fA1, fB0, fB1, fC0, fC1, fD0, fD1;
  if (cw) {
    fA0 = ldg8(ws, GOFF_SCC, wq, 0, lane); fA1 = ldg8(ws, GOFF_SCC, wq, 1, lane);
    fB0 = ldg8(ws, GOFF_SCV, wq, 0, lane); fB1 = ldg8(ws, GOFF_SCV, wq, 1, lane);
    fC0 = ldg8(ws, GOFF_PC0, wq, 0, lane); fC1 = ldg8(ws, GOFF_PC0, wq, 1, lane);
    const int hoff = (wid < 2) ? GOFF_PC1 : GOFF_PV1;
    fD0 = ldg8(ws, hoff, wid & 1, 0, lane); fD1 = ldg8(ws, hoff, wid & 1, 1, lane);
  } else {
    fA0 = ldg8(ws, GOFF_SVV, wq, 0, lane); fA1 = ldg8(ws, GOFF_SVV, wq, 1, lane);
    fB0 = ldg8(ws, GOFF_SVC, wq, 0, lane); fB1 = ldg8(ws, GOFF_SVC, wq, 1, lane);
    fC0 = ldg8(ws, GOFF_PV0, wq, 0, lane); fC1 = ldg8(ws, GOFF_PV0, wq, 1, lane);
    fD0 = fA0; fD1 = fA1;  // unused by v-waves
  }

  // feat A-frag stream: tile row l15 -> batch row br = ((l15>>1)&6)|(l15&1)
  const int brx = ((l15 >> 1) & 6) | (l15 & 1);
  const uint4* xfr = (const uint4*)(ws + WS_X) + (size_t)blockIdx.x * (TT * 64) +
                     brx * 8 + l4;
  half8 fx0, fx1, fy0, fy1;
  {
    union { uint4 u; half8 h; } u0_, u1_;
    u0_.u = xfr[0];
    u1_.u = xfr[4];
    fx0 = u0_.h;
    fx1 = u1_.h;
  }

  // clicks in registers: lane handles rows l4*2 + q (q in {0,1})
  const float* xck = x + (size_t)(r0 + l4 * 2) * ROWSTR + 64;
  float gprev[2] = {0.f, 0.f};  // click(t-1); g(-1)=0
  float gcur[2], gnext[2];
  gcur[0] = xck[0];
  gcur[1] = xck[ROWSTR];

  float st[2] = {0.f, 0.f};     // s_c (c-waves) / s_v (v-waves)
  float hvold[2] = {0.f, 0.f};  // h_v regs (v-waves)
  float fvv[2], ivv[2], ovv[2], gvv[2], psv[2];
  const int col2 = (16 * wq + l15) * 2;
  float2* o2 = (float2*)out;

  __syncthreads();

  for (int t = 0; t < TT; t += 2) {
    STEP(t,     L_HC0, L_HC1, L_HV0, L_HV1, L_Y0C0, L_Y0C1, fx0, fx1, fy0, fy1)
    STEP(t + 1, L_HC1, L_HC0, L_HV1, L_HV0, L_Y0C1, L_Y0C0, fy0, fy1, fx0, fx1)
  }

  // ---- epilogue: out(198), out(199) ----
  if (wid == 7 && lane < 8) {
    float pc = sigm(smf[L_PART + lane] + smf[L_PART + 8 + lane] + bfc);
    float pv = sigm(smf[L_PART + 16 + lane] + smf[L_PART + 24 + lane] + bfv);
    o2[(size_t)(r0 + lane) * TT + (TT - 2)] = make_float2(pc, pv * pc);
  }
  if (!cw) {  // pv0(199): h_v(199) in L_HV0 (t=199 odd -> HVNEW = L_HV0)
    f32x4 apv = sp4(b0u);
    apv = MFMA16(lda(smc, L_HV0, 0, lane), fC0, apv, 0, 0, 0);
    apv = MFMA16(lda(smc, L_HV0, 1, lane), fC1, apv, 0, 0, 0);
#pragma unroll
    for (int q = 0; q < 2; ++q)
      *(_Float16*)(smc + (L_Y0V << 2) + swz((l4 * 4 + q) * 128 + col2)) =
          (_Float16)leaky(apv[q]);
  }
  __syncthreads();
  if (cw) {  // heads(199): y0c(199) in L_Y0C1
    const int asrc = (wid < 2) ? L_Y0C1 : L_Y0V;
    f32x4 ah = sp4(b1h);
    ah = MFMA16(lda(smc, asrc, 0, lane), fD0, ah, 0, 0, 0);
    ah = MFMA16(lda(smc, asrc, 1, lane), fD1, ah, 0, 0, 0);
#pragma unroll
    for (int q = 0; q < 2; ++q) {
      float tq = leaky(ah[q]) * wfh;
      tq += __shfl_xor(tq, 1, 64);
      tq += __shfl_xor(tq, 2, 64);
      tq += __shfl_xor(tq, 4, 64);
      tq += __shfl_xor(tq, 8, 64);
      if (l15 == 0)
        smf[L_PART + ((wid < 2) ? 0 : 16) + (wid & 1) * 8 + (l4 * 2 + q)] = tq;
    }
  }
  __syncthreads();
  if (wid == 0 && lane < 8) {
    float pc = sigm(smf[L_PART + lane] + smf[L_PART + 8 + lane] + bfc);
    float pv = sigm(smf[L_PART + 16 + lane] + smf[L_PART + 24 + lane] + bfv);
    o2[(size_t)(r0 + lane) * TT + (TT - 1)] = make_float2(pc, pv * pc);
  }
}

extern "C" void kernel_launch(void* const* d_in, const int* in_sizes, int n_in,
                              void* d_out, int out_size, void* d_ws, size_t ws_size,
                              hipStream_t stream) {
  const float* x    = (const float*)d_in[0];
  const float* Wxc  = (const float*)d_in[1];
  const float* bxc  = (const float*)d_in[2];
  const float* Whc  = (const float*)d_in[3];
  const float* Wxv  = (const float*)d_in[4];
  const float* bxv  = (const float*)d_in[5];
  const float* Whv  = (const float*)d_in[6];
  const float* Wscc = (const float*)d_in[7];
  const float* Wscv = (const float*)d_in[8];
  const float* Wsvv = (const float*)d_in[9];
  const float* Wsvc = (const float*)d_in[10];
  const float* Wpc0 = (const float*)d_in[11];
  const float* bpc0 = (const float*)d_in[12];
  const float* Wpc1 = (const float*)d_in[13];
  const float* bpc1 = (const float*)d_in[14];
  const float* Wfcc = (const float*)d_in[15];
  const float* bfcc = (const float*)d_in[16];
  const float* Wpv0 = (const float*)d_in[17];
  const float* bpv0 = (const float*)d_in[18];
  const float* Wpv1 = (const float*)d_in[19];
  const float* bpv1 = (const float*)d_in[20];
  const float* Wfcv = (const float*)d_in[21];
  const float* bfcv = (const float*)d_in[22];
  float* out = (float*)d_out;
  unsigned* wsbuf = (unsigned*)d_ws;

  prepack<<<184, 256, 0, stream>>>(Wxc, Wxv, Whc, Whv, Wscc, Wscv, Wsvv, Wsvc,
                                   Wpc0, Wpv0, Wpc1, Wpv1, wsbuf);
  xpack<<<dim3(TT, 256), 256, 0, stream>>>(x, wsbuf + WS_X);

  (void)hipFuncSetAttribute(reinterpret_cast<const void*>(rnn_mfma),
                            hipFuncAttributeMaxDynamicSharedMemorySize, L_TOT * 4);
  rnn_mfma<<<256, 512, L_TOT * 4, stream>>>(
      x, bxc, bxv, bpc0, bpc1, Wfcc, bfcc, bpv0, bpv1, Wfcv, bfcv, wsbuf, out);
}